// Round 4
// baseline (180.979 us; speedup 1.0000x reference)
//
#include <hip/hip_runtime.h>
#include <math.h>

// BNAF layer. B=256, W=64, I=O=64, W_IN=128. M = B*W = 16384.
// Main GEMM: C[m, i*64+o] = Hw[16384,256] @ W2T[256,4096] (34.4 GFLOP bf16 MFMA)
// fused with exp-contraction + sum-exp epilogue; counted-vmcnt LDS pipeline.
// d_out: [output (1M) | logj_out (1M)] fp32.
//
// ws (bytes): W2F @0 (2,097,152) | W1F @2,097,152 (131,072) | BW2F @2,228,224 (32,768)
//             Hw  @2,260,992 (8,388,608 bf16) | Pse @10,649,600 (4,194,304 f32)
// total 14,843,904 B.
//
// Pipeline: out[0:1M] = b1 written by k_hyper (unique writer), then k_fused blocks
// atomicAdd GEMM contributions; Pse accumulates sum-exp via atomics (memset 0 first);
// k_final writes out[1M:2M] = log(Pse).

typedef __attribute__((ext_vector_type(8))) short s16x8;   // 8 bf16 = 4 VGPR
typedef __attribute__((ext_vector_type(4))) float f32x4;   // MFMA C/D frag

__device__ inline unsigned short f2bf(float f) {
  unsigned int u = __float_as_uint(f);
  u += 0x7fffu + ((u >> 16) & 1u);
  return (unsigned short)(u >> 16);
}
__device__ inline float bf2f(unsigned short u) {
  return __uint_as_float(((unsigned int)u) << 16);
}
__device__ inline s16x8 cvt8(float4 a, float4 b) {
  s16x8 v;
  v[0] = (short)f2bf(a.x); v[1] = (short)f2bf(a.y); v[2] = (short)f2bf(a.z); v[3] = (short)f2bf(a.w);
  v[4] = (short)f2bf(b.x); v[5] = (short)f2bf(b.y); v[6] = (short)f2bf(b.z); v[7] = (short)f2bf(b.w);
  return v;
}
__device__ inline void stage16(const unsigned short* gsrc, char* ldst) {
  __builtin_amdgcn_global_load_lds(
      (const __attribute__((address_space(1))) unsigned int*)gsrc,
      (__attribute__((address_space(3))) unsigned int*)ldst, 16, 0, 0);
}

// ---------------- K0: pre-swizzle weights into MFMA B-frag layouts (bf16) ----------------
__global__ __launch_bounds__(256) void k_prep(
    const float* __restrict__ w_w2, const float* __restrict__ w_w1,
    const float* __restrict__ b_w1, const float* __restrict__ b_w2,
    unsigned short* __restrict__ W2F, unsigned short* __restrict__ W1F,
    unsigned short* __restrict__ BW2F) {
  int t = blockIdx.x * 256 + threadIdx.x;
  const float* src; unsigned short* dst;
  if (t < 131072) {            // W2F: chunk c = i*2048 + ks*256 + ot*64 + l
    int c = t, i = c >> 11, ks = (c >> 8) & 7, ot = (c >> 6) & 3, l = c & 63;
    src = w_w2 + (size_t)(i * 64 + ot * 16 + (l & 15)) * 256 + ks * 32 + ((l >> 4) * 8);
    dst = W2F + (size_t)c * 8;
  } else if (t < 139264) {     // W1F: [net][ (nt*4+ks)*64 + l ] frags
    int c = t - 131072, net = c >> 12, r = c & 4095;
    int nt = r >> 8, ks = (r >> 6) & 3, l = r & 63;
    const float* base = net ? b_w1 : w_w1;
    src = base + (size_t)(nt * 16 + (l & 15)) * 128 + ks * 32 + ((l >> 4) * 8);
    dst = W1F + (size_t)net * 32768 + (size_t)(nt * 4 + ks) * 512 + (size_t)l * 8;
  } else if (t < 141312) {     // BW2F: c = (ks*4+ot)*64 + l
    int c = t - 139264, ks = c >> 8, ot = (c >> 6) & 3, l = c & 63;
    src = b_w2 + (size_t)(ot * 16 + (l & 15)) * 256 + ks * 32 + ((l >> 4) * 8);
    dst = BW2F + (size_t)c * 8;
  } else return;
  float4 f0 = *(const float4*)src;
  float4 f1 = *(const float4*)(src + 4);
  *(s16x8*)dst = cvt8(f0, f1);
}

// ---------------- K1: hypernets. net0 -> Hw bf16; net1 -> b1 (written into out[0:1M]) ----
// grid 512: mb = bid>>1 (64 m-rows), net = bid&1. 4 waves x 16 rows.
__global__ __launch_bounds__(256) void k_hyper(
    const float* __restrict__ emb,
    const float* __restrict__ w_b1, const float* __restrict__ b_b1,
    const float* __restrict__ b_b2,
    const unsigned short* __restrict__ W1F, const unsigned short* __restrict__ BW2F,
    unsigned short* __restrict__ Hw, float* __restrict__ out) {
  __shared__ __align__(16) char hsm[131072];  // 64KB W1 frags | 32KB BW2F | 4x8KB Hb bounce
  const int t = threadIdx.x, l = t & 63, lo = t & 15, hi = (t >> 4) & 3, w = t >> 6;
  const int wu = __builtin_amdgcn_readfirstlane(w);
  const int bid = blockIdx.x, mb = bid >> 1, net = bid & 1;
  const int m0 = mb * 64;

  #pragma unroll
  for (int j = 0; j < 16; ++j) {  // 64 W1-frag chunks of 1KB
    int c = wu * 16 + j;
    stage16(W1F + (size_t)net * 32768 + (size_t)c * 512 + l * 8, hsm + c * 1024);
  }
  if (net) {
    #pragma unroll
    for (int j = 0; j < 8; ++j) {  // 32 BW2F chunks
      int c = wu * 8 + j;
      stage16(BW2F + (size_t)c * 512 + l * 8, hsm + 65536 + c * 1024);
    }
  }
  // A frags from emb (fp32 -> bf16 in-register)
  s16x8 ae[4];
  #pragma unroll
  for (int ks = 0; ks < 4; ++ks) {
    const float* p = emb + (size_t)(m0 + w * 16 + lo) * 128 + ks * 32 + hi * 8;
    ae[ks] = cvt8(*(const float4*)p, *(const float4*)(p + 4));
  }
  __syncthreads();  // drains stage16 vmcnt + barrier

  const float* bias = net ? b_b1 : w_b1;
  unsigned short* hb = (unsigned short*)(hsm + 98304 + wu * 8192);  // [16 rows][256] bf16
  #pragma unroll
  for (int nt = 0; nt < 16; ++nt) {
    f32x4 acc = {0.f, 0.f, 0.f, 0.f};
    #pragma unroll
    for (int ks = 0; ks < 4; ++ks) {
      s16x8 b = *(const s16x8*)(hsm + (nt * 4 + ks) * 1024 + l * 16);
      acc = __builtin_amdgcn_mfma_f32_16x16x32_bf16(ae[ks], b, acc, 0, 0, 0);
    }
    float bv = bias[nt * 16 + lo];
    #pragma unroll
    for (int r = 0; r < 4; ++r) {
      float h = tanhf(acc[r] + bv);
      int rloc = hi * 4 + r;
      if (net) hb[rloc * 256 + nt * 16 + lo] = f2bf(h);
      else     Hw[(size_t)(m0 + w * 16 + rloc) * 256 + nt * 16 + lo] = f2bf(h);
    }
  }
  if (net) {  // b1 = Hb @ b_w2^T + b_b2  -> out[m][o]
    s16x8 ab[8];
    #pragma unroll
    for (int ks = 0; ks < 8; ++ks)
      ab[ks] = *(const s16x8*)(hb + lo * 256 + ks * 32 + hi * 8);
    f32x4 acc2[4] = {{0,0,0,0},{0,0,0,0},{0,0,0,0},{0,0,0,0}};
    #pragma unroll
    for (int ks = 0; ks < 8; ++ks)
      #pragma unroll
      for (int ot = 0; ot < 4; ++ot) {
        s16x8 b = *(const s16x8*)(hsm + 65536 + (ks * 4 + ot) * 1024 + l * 16);
        acc2[ot] = __builtin_amdgcn_mfma_f32_16x16x32_bf16(ab[ks], b, acc2[ot], 0, 0, 0);
      }
    #pragma unroll
    for (int ot = 0; ot < 4; ++ot) {
      float bb2 = b_b2[ot * 16 + lo];
      #pragma unroll
      for (int r = 0; r < 4; ++r)
        out[(size_t)(m0 + w * 16 + hi * 4 + r) * 64 + ot * 16 + lo] = acc2[ot][r] + bb2;
    }
  }
}

// ---------------- K2: main GEMM + epilogue, counted-vmcnt 2-buffer pipeline --------------
// grid 512 = mb(128 m-rows; 4 waves x 32) x iq(4; 16 i each).
// LDS: Bbuf[2][32KB] | in_lds [16][128] f32 | el_lds [16][128] bf16 | wb_lds [16][64] f32 = 80KB.
__global__ __launch_bounds__(256, 2) void k_fused(
    const float* __restrict__ input, const float* __restrict__ logj,
    const float* __restrict__ w_b2,
    const unsigned short* __restrict__ W2F, const unsigned short* __restrict__ Hw,
    float* __restrict__ out, float* __restrict__ Pse) {
  __shared__ __align__(16) char smem[81920];
  float* in_lds = (float*)(smem + 65536);
  unsigned short* el_lds = (unsigned short*)(smem + 73728);
  float* wb_lds = (float*)(smem + 77824);

  const int t = threadIdx.x;
  const int l = t & 63, lo = t & 15, hi = (t >> 4) & 3;
  const int w = t >> 6;
  const int wu = __builtin_amdgcn_readfirstlane(w);
  const int bid = blockIdx.x;
  const int mb = bid >> 2, iq = bid & 3;
  const int m0 = mb * 128, i0 = iq * 16;

  // ---- stage input / exp(logj) into [il][row] (conflict-free broadcast layout) ----
  {
    int row = t >> 1, ib = (t & 1) * 8;
    const float* ip = input + (size_t)(m0 + row) * 64 + i0 + ib;
    const float* lp = logj + (size_t)(m0 + row) * 64 + i0 + ib;
    float4 v0 = *(const float4*)ip, v1 = *(const float4*)(ip + 4);
    float4 g0 = *(const float4*)lp, g1 = *(const float4*)(lp + 4);
    float vi[8] = {v0.x, v0.y, v0.z, v0.w, v1.x, v1.y, v1.z, v1.w};
    float gj[8] = {g0.x, g0.y, g0.z, g0.w, g1.x, g1.y, g1.z, g1.w};
    #pragma unroll
    for (int j = 0; j < 8; ++j) {
      in_lds[(ib + j) * 128 + row] = vi[j];
      el_lds[(ib + j) * 128 + row] = f2bf(__expf(gj[j]));
    }
  }
  {  // wb slice [16][64]
    int il = t >> 4, oc = (t & 15) * 4;
    float4 v = *(const float4*)(w_b2 + (size_t)(i0 + il) * 64 + oc);
    *(float4*)(wb_lds + il * 64 + oc) = v;
  }
  // ---- A-frags from Hw (coalesced 16B/lane), live across whole loop ----
  s16x8 aw[2][8];
  #pragma unroll
  for (int mt = 0; mt < 2; ++mt)
    #pragma unroll
    for (int ks = 0; ks < 8; ++ks)
      aw[mt][ks] = *(const s16x8*)(Hw + (size_t)(m0 + w * 32 + mt * 16 + lo) * 256 + ks * 32 + hi * 8);

  // drain ALL vmem + lds before the counted pipeline starts
  asm volatile("s_waitcnt vmcnt(0) lgkmcnt(0)" ::: "memory");
  __builtin_amdgcn_sched_barrier(0);

  // ---- prologue: stage s0 -> buf0, s1 -> buf1 (8 x 1KB chunks per wave per slice) ----
  #pragma unroll
  for (int j = 0; j < 8; ++j) {
    int c = wu * 8 + j;
    stage16(W2F + (size_t)i0 * 16384 + (size_t)c * 512 + l * 8, smem + c * 1024);
  }
  #pragma unroll
  for (int j = 0; j < 8; ++j) {
    int c = wu * 8 + j;
    stage16(W2F + (size_t)(i0 + 1) * 16384 + (size_t)c * 512 + l * 8, smem + 32768 + c * 1024);
  }

  float outa[2][4][4] = {}, se[2][4][4] = {};
  f32x4 accA[2][4], accB[2][4];

  auto epil = [&](int il, f32x4 (&acc)[2][4]) {
    #pragma unroll
    for (int mt = 0; mt < 2; ++mt)
      #pragma unroll
      for (int r = 0; r < 4; ++r) {
        int rl = w * 32 + mt * 16 + hi * 4 + r;
        float xin = in_lds[il * 128 + rl];
        float el = bf2f(el_lds[il * 128 + rl]);
        #pragma unroll
        for (int ot = 0; ot < 4; ++ot) {
          float e1 = __expf(acc[mt][ot][r] + wb_lds[il * 64 + ot * 16 + lo]);
          outa[mt][ot][r] = fmaf(xin, e1, outa[mt][ot][r]);
          se[mt][ot][r] = fmaf(el, e1, se[mt][ot][r]);
        }
      }
  };

  auto iter = [&](int il, f32x4 (&cur)[2][4], f32x4 (&prv)[2][4], bool doPrev, int bufsel) {
    if (il < 15) asm volatile("s_waitcnt vmcnt(8)" ::: "memory");  // oldest slice done; newest stays in flight
    else         asm volatile("s_waitcnt vmcnt(0)" ::: "memory");
    __builtin_amdgcn_s_barrier();
    const char* bb = smem + bufsel * 32768;
    #pragma unroll
    for (int mt = 0; mt < 2; ++mt)
      #pragma unroll
      for (int ot = 0; ot < 4; ++ot) cur[mt][ot] = (f32x4){0.f, 0.f, 0.f, 0.f};
    __builtin_amdgcn_s_setprio(1);
    #pragma unroll
    for (int ks = 0; ks < 8; ++ks)
      #pragma unroll
      for (int ot = 0; ot < 4; ++ot) {
        s16x8 b = *(const s16x8*)(bb + (ks * 4 + ot) * 1024 + l * 16);
        cur[0][ot] = __builtin_amdgcn_mfma_f32_16x16x32_bf16(aw[0][ks], b, cur[0][ot], 0, 0, 0);
        cur[1][ot] = __builtin_amdgcn_mfma_f32_16x16x32_bf16(aw[1][ks], b, cur[1][ot], 0, 0, 0);
      }
    __builtin_amdgcn_s_setprio(0);
    if (doPrev) epil(il - 1, prv);   // VALU overlaps matrix pipe
    __builtin_amdgcn_s_barrier();    // all waves done reading bufsel
    if (il <= 13) {                  // stage s_{il+2} into the buffer just freed
      const unsigned short* Bn = W2F + (size_t)(i0 + il + 2) * 16384;
      #pragma unroll
      for (int j = 0; j < 8; ++j) {
        int c = wu * 8 + j;
        stage16(Bn + (size_t)c * 512 + l * 8, smem + bufsel * 32768 + c * 1024);
      }
    }
  };

  for (int ii = 0; ii < 8; ++ii) {
    iter(2 * ii, accA, accB, ii > 0, 0);
    iter(2 * ii + 1, accB, accA, true, 1);
  }
  epil(15, accB);

  // ---- accumulate into out (b1 pre-written by k_hyper) and Pse (memset 0) ----
  #pragma unroll
  for (int mt = 0; mt < 2; ++mt)
    #pragma unroll
    for (int ot = 0; ot < 4; ++ot)
      #pragma unroll
      for (int r = 0; r < 4; ++r) {
        int m = m0 + w * 32 + mt * 16 + hi * 4 + r;
        int o = ot * 16 + lo;
        atomicAdd(out + (size_t)m * 64 + o, outa[mt][ot][r]);
        atomicAdd(Pse + (size_t)m * 64 + o, se[mt][ot][r]);
      }
}

// ---------------- K3: logj_out = log(sum-exp) ----------------
__global__ __launch_bounds__(256) void k_final(const float* __restrict__ Pse,
                                               float* __restrict__ out) {
  int idx = (blockIdx.x * 256 + threadIdx.x) * 4;
  float4 e = *(const float4*)(Pse + idx);
  float4 lg;
  lg.x = __logf(e.x); lg.y = __logf(e.y); lg.z = __logf(e.z); lg.w = __logf(e.w);
  *(float4*)(out + 1048576 + idx) = lg;
}

extern "C" void kernel_launch(void* const* d_in, const int* in_sizes, int n_in,
                              void* d_out, int out_size, void* d_ws, size_t ws_size,
                              hipStream_t stream) {
  const float* input = (const float*)d_in[0];
  const float* w_emb = (const float*)d_in[1];
  const float* logj  = (const float*)d_in[2];
  const float* w_w1  = (const float*)d_in[3];
  const float* w_b1  = (const float*)d_in[4];
  const float* w_w2  = (const float*)d_in[5];
  const float* w_b2  = (const float*)d_in[6];
  const float* b_w1  = (const float*)d_in[7];
  const float* b_b1  = (const float*)d_in[8];
  const float* b_w2  = (const float*)d_in[9];
  const float* b_b2  = (const float*)d_in[10];
  float* out = (float*)d_out;

  char* wsb = (char*)d_ws;
  unsigned short* W2F  = (unsigned short*)(wsb);
  unsigned short* W1F  = (unsigned short*)(wsb + 2097152);
  unsigned short* BW2F = (unsigned short*)(wsb + 2228224);
  unsigned short* Hw   = (unsigned short*)(wsb + 2260992);
  float*          Pse  = (float*)(wsb + 10649600);

  hipMemsetAsync(Pse, 0, 4194304, stream);
  hipLaunchKernelGGL(k_prep, dim3(552), dim3(256), 0, stream,
                     w_w2, w_w1, b_w1, b_w2, W2F, W1F, BW2F);
  hipLaunchKernelGGL(k_hyper, dim3(512), dim3(256), 0, stream,
                     w_emb, w_b1, b_b1, b_b2, W1F, BW2F, Hw, out);
  hipLaunchKernelGGL(k_fused, dim3(512), dim3(256), 0, stream,
                     input, logj, w_b2, W2F, Hw, out, Pse);
  hipLaunchKernelGGL(k_final, dim3(1024), dim3(256), 0, stream, Pse, out);
}

// Round 5
// 160.362 us; speedup vs baseline: 1.1286x; 1.1286x over previous
//
#include <hip/hip_runtime.h>
#include <math.h>

// BNAF layer. B=256, W=64, I=O=64, W_IN=128. M = 16384.
// R5: swapped-operand MFMA (A = w_w2 [o x k], B = HwT [k x m] resident in VGPRs),
// wave-private o-quarter pipelines, barrier-free hot loop, counted vmcnt(8).
// d_out: [output (1M) | logj_out (1M)] fp32.
//
// ws (bytes): W2F @0 (2,097,152 bf16 A-frags) | Hw @2,097,152 (8,388,608 bf16 [m][256])
//             b1 @10,485,760 (4,194,304 f32) | Poa @14,680,064 (2x 4,194,304 f32)
//             Pse @23,068,672 (2x 4,194,304 f32)  -- total 31,457,280 B.

typedef __attribute__((ext_vector_type(8))) short s16x8;   // 8 bf16 = 4 VGPR
typedef __attribute__((ext_vector_type(4))) float f32x4;   // MFMA C/D frag

__device__ inline unsigned short f2bf(float f) {
  unsigned int u = __float_as_uint(f);
  u += 0x7fffu + ((u >> 16) & 1u);
  return (unsigned short)(u >> 16);
}
__device__ inline float bf2f(unsigned short u) { return __uint_as_float(((unsigned int)u) << 16); }
__device__ inline s16x8 cvt8(float4 a, float4 b) {
  s16x8 v;
  v[0] = (short)f2bf(a.x); v[1] = (short)f2bf(a.y); v[2] = (short)f2bf(a.z); v[3] = (short)f2bf(a.w);
  v[4] = (short)f2bf(b.x); v[5] = (short)f2bf(b.y); v[6] = (short)f2bf(b.z); v[7] = (short)f2bf(b.w);
  return v;
}
__device__ inline float fast_tanh(float x) {   // tanh via exp2-path; |err| ~1e-6 rel
  float t = __expf(2.0f * x);
  return __fdividef(t - 1.0f, t + 1.0f);
}
__device__ inline void stage16(const unsigned short* gsrc, char* ldst) {
  __builtin_amdgcn_global_load_lds(
      (const __attribute__((address_space(1))) unsigned int*)gsrc,
      (__attribute__((address_space(3))) unsigned int*)ldst, 16, 0, 0);
}

// ---------------- K0: fused prep (blocks 0..63) + hypernets (blocks 64..319) ----------------
// prep: block = one i: w_w2 rows [i*64, i*64+64) -> bf16 A-frags W2F[(i*4+oq)*8+ks][l*8].
//   A-frag (16x16x32, M-dim = o): lane l holds o = oq*16+(l&15), k = ks*32+(l>>4)*8..+8.
// hyper: net = w/b; wave = 32 m rows. B-frags (n = l&15 rows of w1) read DIRECTLY from
//   global f32 + cvt (L2-resident, reused across 2 m-tiles). w-net -> Hw bf16 [m][256];
//   b-net -> LDS bounce -> b1 = Hb @ b_w2^T + b_b2 -> b1 buffer.
__global__ __launch_bounds__(256) void k_pre(
    const float* __restrict__ w_w2, const float* __restrict__ emb,
    const float* __restrict__ w_w1, const float* __restrict__ w_b1,
    const float* __restrict__ b_w1, const float* __restrict__ b_b1,
    const float* __restrict__ b_w2, const float* __restrict__ b_b2,
    unsigned short* __restrict__ W2F, unsigned short* __restrict__ Hw,
    float* __restrict__ b1out) {
  __shared__ __align__(16) char lsm[67584];   // prep: f32 [64][264] ; hyper: u16 [4][32][264]
  const int t = threadIdx.x, l = t & 63, lo = t & 15, hi = (t >> 4) & 3, w = t >> 6;
  const int bid = blockIdx.x;

  if (bid < 64) {  // ---- prep for i = bid ----
    const int i = bid;
    float* ld = (float*)lsm;
    const float* src = w_w2 + (size_t)i * 16384;
    #pragma unroll
    for (int v = 0; v < 16; ++v) {            // coalesced 64KB read -> padded LDS
      int flat = t * 64 + v * 4;
      int row = flat >> 8, col = flat & 255;
      *(float4*)(ld + row * 264 + col) = *(const float4*)(src + flat);
    }
    __syncthreads();
    #pragma unroll
    for (int ks = 0; ks < 8; ++ks) {          // emit frags, coalesced 16B/lane stores
      const float* p = ld + (w * 16 + lo) * 264 + ks * 32 + hi * 8;
      s16x8 vfr = cvt8(*(const float4*)p, *(const float4*)(p + 4));
      *(s16x8*)(W2F + ((size_t)(i * 4 + w) * 8 + ks) * 512 + (size_t)l * 8) = vfr;
    }
    return;
  }

  // ---- hyper ----
  const int hb_id = bid - 64, net = hb_id & 1, mb = hb_id >> 1;
  const int mw0 = mb * 128 + w * 32;
  const float* W1 = net ? b_w1 : w_w1;
  const float* B1 = net ? b_b1 : w_b1;
  s16x8 ae[2][4];
  #pragma unroll
  for (int mt = 0; mt < 2; ++mt)
    #pragma unroll
    for (int ks = 0; ks < 4; ++ks) {
      const float* p = emb + (size_t)(mw0 + mt * 16 + lo) * 128 + ks * 32 + hi * 8;
      ae[mt][ks] = cvt8(*(const float4*)p, *(const float4*)(p + 4));
    }
  unsigned short* hb = (unsigned short*)lsm + (size_t)w * 32 * 264;  // [32][264]
  #pragma unroll
  for (int nt = 0; nt < 16; ++nt) {
    f32x4 acc[2] = {{0,0,0,0},{0,0,0,0}};
    #pragma unroll
    for (int ks = 0; ks < 4; ++ks) {
      const float* bp = W1 + (size_t)(nt * 16 + lo) * 128 + ks * 32 + hi * 8;
      s16x8 bf = cvt8(*(const float4*)bp, *(const float4*)(bp + 4));
      acc[0] = __builtin_amdgcn_mfma_f32_16x16x32_bf16(ae[0][ks], bf, acc[0], 0, 0, 0);
      acc[1] = __builtin_amdgcn_mfma_f32_16x16x32_bf16(ae[1][ks], bf, acc[1], 0, 0, 0);
    }
    float bv = B1[nt * 16 + lo];
    #pragma unroll
    for (int mt = 0; mt < 2; ++mt)
      #pragma unroll
      for (int r = 0; r < 4; ++r) {
        float h = fast_tanh(acc[mt][r] + bv);
        if (net) hb[(mt * 16 + hi * 4 + r) * 264 + nt * 16 + lo] = f2bf(h);
        else Hw[(size_t)(mw0 + mt * 16 + hi * 4 + r) * 256 + nt * 16 + lo] = f2bf(h);
      }
  }
  if (net) {  // b1 = Hb @ b_w2^T + b_b2
    #pragma unroll
    for (int ot = 0; ot < 4; ++ot) {
      f32x4 acc[2] = {{0,0,0,0},{0,0,0,0}};
      #pragma unroll
      for (int ks = 0; ks < 8; ++ks) {
        const float* bp = b_w2 + (size_t)(ot * 16 + lo) * 256 + ks * 32 + hi * 8;
        s16x8 bf = cvt8(*(const float4*)bp, *(const float4*)(bp + 4));
        s16x8 a0 = *(const s16x8*)(hb + (0 * 16 + lo) * 264 + ks * 32 + hi * 8);
        s16x8 a1 = *(const s16x8*)(hb + (1 * 16 + lo) * 264 + ks * 32 + hi * 8);
        acc[0] = __builtin_amdgcn_mfma_f32_16x16x32_bf16(a0, bf, acc[0], 0, 0, 0);
        acc[1] = __builtin_amdgcn_mfma_f32_16x16x32_bf16(a1, bf, acc[1], 0, 0, 0);
      }
      float bb = b_b2[ot * 16 + lo];
      #pragma unroll
      for (int mt = 0; mt < 2; ++mt)
        #pragma unroll
        for (int r = 0; r < 4; ++r)
          b1out[(size_t)(mw0 + mt * 16 + hi * 4 + r) * 64 + ot * 16 + lo] = acc[mt][r] + bb;
    }
  }
}

// ---------------- K1: main fused GEMM, wave-private barrier-free pipeline ----------------
// grid 512 = mb(256: 64 m-rows) x iq(2: 32 i). 4 waves = 4 o-quarters (16 o each).
// Wave: B = HwT resident (4 nt x 8 ks frags = 128 VGPR); A-slice (16o x 256k bf16 = 8KB)
// streamed per i into PRIVATE LDS dbuf via global_load_lds; own vmcnt(8); NO barriers.
// C[o][m]: row = o = (l>>4)*4+r, col = m = nt*16+(l&15). Epilogue: e1 = exp(acc)*ewb;
// outa += xin*e1; se += elj*e1. Partial stores (iq-disjoint), summed by k_final.
__global__ __launch_bounds__(256, 2) void k_fused(
    const float* __restrict__ input, const float* __restrict__ logj,
    const float* __restrict__ w_b2,
    const unsigned short* __restrict__ W2F, const unsigned short* __restrict__ Hw,
    float* __restrict__ Poa, float* __restrict__ Pse) {
  __shared__ __align__(16) char smem[81920];  // 4x16KB wave dbufs | xin 8KB | elj 4KB | ewb 4KB
  float* xin_l = (float*)(smem + 65536);                     // [32 i][64 m]
  unsigned short* elj_l = (unsigned short*)(smem + 73728);   // [32 i][64 m] bf16
  unsigned short* ewb_l = (unsigned short*)(smem + 77824);   // [32 i][64 o] bf16

  const int t = threadIdx.x, l = t & 63, lo = t & 15, hi = (t >> 4) & 3;
  const int w = t >> 6, wu = __builtin_amdgcn_readfirstlane(w);
  const int bid = blockIdx.x;
  const int mb = bid >> 1, iq = bid & 1;
  const int m0 = mb * 64, i0 = iq * 32;

  {  // tables: xin / exp(logj) keyed [i][m]; ewb = exp(w_b2) keyed [i][o]
    int mm = t & 63, ib = (t >> 6) * 8;
    const float* ip = input + (size_t)(m0 + mm) * 64 + i0 + ib;
    const float* lp = logj + (size_t)(m0 + mm) * 64 + i0 + ib;
    float4 v0 = *(const float4*)ip, v1 = *(const float4*)(ip + 4);
    float4 g0 = *(const float4*)lp, g1 = *(const float4*)(lp + 4);
    float vi[8] = {v0.x, v0.y, v0.z, v0.w, v1.x, v1.y, v1.z, v1.w};
    float gj[8] = {g0.x, g0.y, g0.z, g0.w, g1.x, g1.y, g1.z, g1.w};
    #pragma unroll
    for (int j = 0; j < 8; ++j) {
      xin_l[(ib + j) * 64 + mm] = vi[j];
      elj_l[(ib + j) * 64 + mm] = f2bf(__expf(gj[j]));
    }
    int il = t >> 3, ob = (t & 7) * 8;
    const float* wp = w_b2 + (size_t)(i0 + il) * 64 + ob;
    float4 e0 = *(const float4*)wp, e1 = *(const float4*)(wp + 4);
    float ev[8] = {e0.x, e0.y, e0.z, e0.w, e1.x, e1.y, e1.z, e1.w};
    #pragma unroll
    for (int j = 0; j < 8; ++j) ewb_l[il * 64 + ob + j] = f2bf(__expf(ev[j]));
  }

  // B-resident: HwT frags, loop-invariant (n = m = l&15 rows of Hw; 16B contiguous in k)
  s16x8 bh[4][8];
  #pragma unroll
  for (int nt = 0; nt < 4; ++nt)
    #pragma unroll
    for (int ks = 0; ks < 8; ++ks)
      bh[nt][ks] = *(const s16x8*)(Hw + (size_t)(m0 + nt * 16 + lo) * 256 + ks * 32 + hi * 8);

  __syncthreads();  // tables visible; drains all vmem -> counted pipeline starts clean

  char* Ab = smem + wu * 16384;  // private [2][8KB]
  #pragma unroll
  for (int p = 0; p < 2; ++p)
    #pragma unroll
    for (int ks = 0; ks < 8; ++ks)
      stage16(W2F + ((size_t)(i0 + p) * 4 + wu) * 4096 + ks * 512 + (size_t)l * 8,
              Ab + p * 8192 + ks * 1024);

  f32x4 outa[4] = {{0,0,0,0},{0,0,0,0},{0,0,0,0},{0,0,0,0}};
  f32x4 sea[4] = {{0,0,0,0},{0,0,0,0},{0,0,0,0},{0,0,0,0}};

  for (int il = 0; il < 32; ++il) {
    if (il < 31) asm volatile("s_waitcnt vmcnt(8)" ::: "memory");  // this slice landed; next in flight
    else         asm volatile("s_waitcnt vmcnt(0)" ::: "memory");
    __builtin_amdgcn_sched_barrier(0);
    const char* ab = Ab + (il & 1) * 8192;

    float xin[4], el[4], ew[4];
    #pragma unroll
    for (int nt = 0; nt < 4; ++nt) {
      xin[nt] = xin_l[il * 64 + nt * 16 + lo];
      el[nt] = bf2f(elj_l[il * 64 + nt * 16 + lo]);
    }
    {
      ushort4 uv = *(const ushort4*)(ewb_l + il * 64 + wu * 16 + hi * 4);
      ew[0] = bf2f(uv.x); ew[1] = bf2f(uv.y); ew[2] = bf2f(uv.z); ew[3] = bf2f(uv.w);
    }
    f32x4 acc[4] = {{0,0,0,0},{0,0,0,0},{0,0,0,0},{0,0,0,0}};
    #pragma unroll
    for (int ks = 0; ks < 8; ++ks) {
      s16x8 a = *(const s16x8*)(ab + ks * 1024 + l * 16);
      acc[0] = __builtin_amdgcn_mfma_f32_16x16x32_bf16(a, bh[0][ks], acc[0], 0, 0, 0);
      acc[1] = __builtin_amdgcn_mfma_f32_16x16x32_bf16(a, bh[1][ks], acc[1], 0, 0, 0);
      acc[2] = __builtin_amdgcn_mfma_f32_16x16x32_bf16(a, bh[2][ks], acc[2], 0, 0, 0);
      acc[3] = __builtin_amdgcn_mfma_f32_16x16x32_bf16(a, bh[3][ks], acc[3], 0, 0, 0);
    }
    asm volatile("s_waitcnt lgkmcnt(0)" ::: "memory");  // ds_reads retired before WAR overwrite
    __builtin_amdgcn_sched_barrier(0);
    if (il < 30) {
      size_t gb = ((size_t)(i0 + il + 2) * 4 + wu) * 4096;
      #pragma unroll
      for (int ks = 0; ks < 8; ++ks)
        stage16(W2F + gb + ks * 512 + (size_t)l * 8, Ab + (il & 1) * 8192 + ks * 1024);
    }
    #pragma unroll
    for (int nt = 0; nt < 4; ++nt)
      #pragma unroll
      for (int r = 0; r < 4; ++r) {
        float e1 = __expf(acc[nt][r]) * ew[r];
        outa[nt][r] = fmaf(xin[nt], e1, outa[nt][r]);
        sea[nt][r] = fmaf(el[nt], e1, sea[nt][r]);
      }
  }

  const int o0 = wu * 16 + hi * 4;
  #pragma unroll
  for (int nt = 0; nt < 4; ++nt) {
    size_t base = (size_t)(m0 + nt * 16 + lo) * 64 + o0;
    *(f32x4*)(Poa + (size_t)iq * 1048576 + base) = outa[nt];
    *(f32x4*)(Pse + (size_t)iq * 1048576 + base) = sea[nt];
  }
}

// ---------------- K2: combine partials ----------------
__global__ __launch_bounds__(256) void k_final(
    const float* __restrict__ b1, const float* __restrict__ Poa,
    const float* __restrict__ Pse, float* __restrict__ out) {
  int idx = (blockIdx.x * 256 + threadIdx.x) * 4;
  float4 bb = *(const float4*)(b1 + idx);
  float4 a0 = *(const float4*)(Poa + idx);
  float4 a1 = *(const float4*)(Poa + 1048576 + idx);
  float4 s0 = *(const float4*)(Pse + idx);
  float4 s1 = *(const float4*)(Pse + 1048576 + idx);
  float4 o1, o2;
  o1.x = bb.x + a0.x + a1.x; o1.y = bb.y + a0.y + a1.y;
  o1.z = bb.z + a0.z + a1.z; o1.w = bb.w + a0.w + a1.w;
  o2.x = __logf(s0.x + s1.x); o2.y = __logf(s0.y + s1.y);
  o2.z = __logf(s0.z + s1.z); o2.w = __logf(s0.w + s1.w);
  *(float4*)(out + idx) = o1;
  *(float4*)(out + 1048576 + idx) = o2;
}

extern "C" void kernel_launch(void* const* d_in, const int* in_sizes, int n_in,
                              void* d_out, int out_size, void* d_ws, size_t ws_size,
                              hipStream_t stream) {
  const float* input = (const float*)d_in[0];
  const float* w_emb = (const float*)d_in[1];
  const float* logj  = (const float*)d_in[2];
  const float* w_w1  = (const float*)d_in[3];
  const float* w_b1  = (const float*)d_in[4];
  const float* w_w2  = (const float*)d_in[5];
  const float* w_b2  = (const float*)d_in[6];
  const float* b_w1  = (const float*)d_in[7];
  const float* b_b1  = (const float*)d_in[8];
  const float* b_w2  = (const float*)d_in[9];
  const float* b_b2  = (const float*)d_in[10];
  float* out = (float*)d_out;

  char* wsb = (char*)d_ws;
  unsigned short* W2F = (unsigned short*)(wsb);
  unsigned short* Hw  = (unsigned short*)(wsb + 2097152);
  float*          b1  = (float*)(wsb + 10485760);
  float*          Poa = (float*)(wsb + 14680064);
  float*          Pse = (float*)(wsb + 23068672);

  hipLaunchKernelGGL(k_pre, dim3(320), dim3(256), 0, stream,
                     w_w2, w_emb, w_w1, w_b1, b_w1, b_b1, b_w2, b_b2, W2F, Hw, b1);
  hipLaunchKernelGGL(k_fused, dim3(512), dim3(256), 0, stream,
                     input, logj, w_b2, W2F, Hw, Poa, Pse);
  hipLaunchKernelGGL(k_final, dim3(1024), dim3(256), 0, stream, b1, Poa, Pse, out);
}

// Round 6
// 160.116 us; speedup vs baseline: 1.1303x; 1.0015x over previous
//
#include <hip/hip_runtime.h>
#include <math.h>

// BNAF layer. B=256, W=64, I=O=64, W_IN=128. M = 16384.
// R6: R5 structure (swapped-operand MFMA, bh resident, wave-private, barrier-free)
// + deep 16-slot ring pipeline (4 chunks / 16 loads in flight, vmcnt(12))
// + rebuilt k_pre (LDS-staged w1 frags, 512 hyper blocks).
// d_out: [output (1M) | logj_out (1M)] fp32.
//
// ws (bytes): W2F @0 (2,097,152 bf16 A-frags) | Hw @2,097,152 (8,388,608 bf16 [m][256])
//             b1 @10,485,760 (4,194,304 f32) | Poa @14,680,064 (2x 4,194,304 f32)
//             Pse @23,068,672 (2x 4,194,304 f32)  -- total 31,457,280 B.

typedef __attribute__((ext_vector_type(8))) short s16x8;   // 8 bf16 = 4 VGPR
typedef __attribute__((ext_vector_type(4))) float f32x4;   // MFMA C/D frag

#define WAITV(N) asm volatile("s_waitcnt vmcnt(" #N ")" ::: "memory")

__device__ inline unsigned short f2bf(float f) {
  unsigned int u = __float_as_uint(f);
  u += 0x7fffu + ((u >> 16) & 1u);
  return (unsigned short)(u >> 16);
}
__device__ inline float bf2f(unsigned short u) { return __uint_as_float(((unsigned int)u) << 16); }
__device__ inline s16x8 cvt8(float4 a, float4 b) {
  s16x8 v;
  v[0] = (short)f2bf(a.x); v[1] = (short)f2bf(a.y); v[2] = (short)f2bf(a.z); v[3] = (short)f2bf(a.w);
  v[4] = (short)f2bf(b.x); v[5] = (short)f2bf(b.y); v[6] = (short)f2bf(b.z); v[7] = (short)f2bf(b.w);
  return v;
}
__device__ inline float fast_tanh(float x) {
  float t = __expf(2.0f * x);
  return __fdividef(t - 1.0f, t + 1.0f);
}
__device__ inline void stage16(const unsigned short* gsrc, char* ldst) {
  __builtin_amdgcn_global_load_lds(
      (const __attribute__((address_space(1))) unsigned int*)gsrc,
      (__attribute__((address_space(3))) unsigned int*)ldst, 16, 0, 0);
}

// ---------------- K0: prep (bid<64) + hypernets (bid 64..575) ----------------
// prep: block = one i of w_w2 -> bf16 A-frags W2F[((i*4+oq)*8+ks)*512 + l*8]
//   A-frag (16x16x32, M-dim=o): lane l holds o = oq*16+(l&15), k = ks*32+(l>>4)*8..+8.
// hyper: bid-64 = mb*2+net; 64 m-rows/block, wave = 16 rows. w1 staged ONCE into
//   LDS as bf16 frags (64x1KB), then MFMA loop reads LDS. w-net -> Hw; b-net keeps
//   h in regs, reuses frag-LDS as bounce after barrier, emits b1 = Hb@b_w2^T + b_b2.
__global__ __launch_bounds__(256) void k_pre(
    const float* __restrict__ w_w2, const float* __restrict__ emb,
    const float* __restrict__ w_w1, const float* __restrict__ w_b1,
    const float* __restrict__ b_w1, const float* __restrict__ b_b1,
    const float* __restrict__ b_w2, const float* __restrict__ b_b2,
    unsigned short* __restrict__ W2F, unsigned short* __restrict__ Hw,
    float* __restrict__ b1out) {
  __shared__ __align__(16) char lsm[67584];   // prep: f32 [64][264]; hyper: 64x1KB frags
  const int t = threadIdx.x, l = t & 63, lo = t & 15, hi = (t >> 4) & 3, w = t >> 6;
  const int wu = __builtin_amdgcn_readfirstlane(w);
  const int bid = blockIdx.x;

  if (bid < 64) {  // ---- prep for i = bid ----
    const int i = bid;
    float* ld = (float*)lsm;
    const float* src = w_w2 + (size_t)i * 16384;
    #pragma unroll
    for (int v = 0; v < 16; ++v) {            // fully coalesced 64KB read
      int flat = v * 1024 + t * 4;
      int row = flat >> 8, col = flat & 255;
      *(float4*)(ld + row * 264 + col) = *(const float4*)(src + flat);
    }
    __syncthreads();
    #pragma unroll
    for (int ks = 0; ks < 8; ++ks) {
      const float* p = ld + (w * 16 + lo) * 264 + ks * 32 + hi * 8;
      s16x8 vfr = cvt8(*(const float4*)p, *(const float4*)(p + 4));
      *(s16x8*)(W2F + ((size_t)(i * 4 + w) * 8 + ks) * 512 + (size_t)l * 8) = vfr;
    }
    return;
  }

  // ---- hyper ----
  const int hb_id = bid - 64, net = hb_id & 1, mb = hb_id >> 1;
  const int mw0 = mb * 64 + w * 16;
  const float* W1 = net ? b_w1 : w_w1;
  const float* B1 = net ? b_b1 : w_b1;

  #pragma unroll
  for (int j = 0; j < 16; ++j) {   // stage w1 -> bf16 frags (chunk c = nt*4+ks)
    int c = wu * 16 + j, nt = c >> 2, ks = c & 3;
    const float* bp = W1 + (size_t)(nt * 16 + lo) * 128 + ks * 32 + hi * 8;
    s16x8 f = cvt8(*(const float4*)bp, *(const float4*)(bp + 4));
    *(s16x8*)(lsm + c * 1024 + l * 16) = f;
  }
  s16x8 ae[4];
  #pragma unroll
  for (int ks = 0; ks < 4; ++ks) {
    const float* p = emb + (size_t)(mw0 + lo) * 128 + ks * 32 + hi * 8;
    ae[ks] = cvt8(*(const float4*)p, *(const float4*)(p + 4));
  }
  __syncthreads();

  unsigned short hreg[16][4];
  #pragma unroll
  for (int nt = 0; nt < 16; ++nt) {
    f32x4 acc = {0.f, 0.f, 0.f, 0.f};
    #pragma unroll
    for (int ks = 0; ks < 4; ++ks) {
      s16x8 b = *(const s16x8*)(lsm + (nt * 4 + ks) * 1024 + l * 16);
      acc = __builtin_amdgcn_mfma_f32_16x16x32_bf16(ae[ks], b, acc, 0, 0, 0);
    }
    float bv = B1[nt * 16 + lo];
    #pragma unroll
    for (int r = 0; r < 4; ++r) {
      float h = fast_tanh(acc[r] + bv);
      if (net) hreg[nt][r] = f2bf(h);
      else Hw[(size_t)(mw0 + hi * 4 + r) * 256 + nt * 16 + lo] = f2bf(h);
    }
  }
  if (net) {                       // b1 = Hb @ b_w2^T + b_b2
    __syncthreads();               // all waves done reading w1 frags -> reuse LDS
    unsigned short* hb = (unsigned short*)(lsm) + (size_t)wu * 4224;  // [16][264]
    #pragma unroll
    for (int nt = 0; nt < 16; ++nt)
      #pragma unroll
      for (int r = 0; r < 4; ++r)
        hb[(hi * 4 + r) * 264 + nt * 16 + lo] = hreg[nt][r];
    s16x8 ab[8];
    __builtin_amdgcn_s_waitcnt(0);  // lgkm handled by compiler on reads below
    #pragma unroll
    for (int ks = 0; ks < 8; ++ks)
      ab[ks] = *(const s16x8*)(hb + lo * 264 + ks * 32 + hi * 8);
    #pragma unroll
    for (int ot = 0; ot < 4; ++ot) {
      f32x4 acc2 = {0.f, 0.f, 0.f, 0.f};
      #pragma unroll
      for (int ks = 0; ks < 8; ++ks) {
        const float* bp = b_w2 + (size_t)(ot * 16 + lo) * 256 + ks * 32 + hi * 8;
        s16x8 bf = cvt8(*(const float4*)bp, *(const float4*)(bp + 4));
        acc2 = __builtin_amdgcn_mfma_f32_16x16x32_bf16(ab[ks], bf, acc2, 0, 0, 0);
      }
      float bb = b_b2[ot * 16 + lo];
      #pragma unroll
      for (int r = 0; r < 4; ++r)
        b1out[(size_t)(mw0 + hi * 4 + r) * 64 + ot * 16 + lo] = acc2[r] + bb;
    }
  }
}

// ---------------- K1: main fused GEMM, wave-private deep-ring pipeline ----------------
// grid 512 = mb(256: 64 m) x iq(2: 32 i). 4 waves = 4 o-quarters. bh (HwT) resident
// (128 AGPR). A stream: 16-slot x 1KB LDS ring/wave, 16 loads in flight, consumed in
// 4-frag chunks with vmcnt(12); tail 12/8/4/0. NO barriers, NO other VMEM in loop.
__global__ __launch_bounds__(256, 2) void k_fused(
    const float* __restrict__ input, const float* __restrict__ logj,
    const float* __restrict__ w_b2,
    const unsigned short* __restrict__ W2F, const unsigned short* __restrict__ Hw,
    float* __restrict__ Poa, float* __restrict__ Pse) {
  __shared__ __align__(16) char smem[81920];  // 4x16KB rings | xin 8K f32 | elj 4K | ewb 4K
  float* xin_l = (float*)(smem + 65536);                     // [32 i][64 m]
  unsigned short* elj_l = (unsigned short*)(smem + 73728);   // [32 i][64 m] bf16
  unsigned short* ewb_l = (unsigned short*)(smem + 77824);   // [32 i][64 o] bf16

  const int t = threadIdx.x, l = t & 63, lo = t & 15, hi = (t >> 4) & 3;
  const int w = t >> 6, wu = __builtin_amdgcn_readfirstlane(w);
  const int bid = blockIdx.x;
  const int mb = bid >> 1, iq = bid & 1;
  const int m0 = mb * 64, i0 = iq * 32;

  {  // tables
    int mm = t & 63, ib = (t >> 6) * 8;
    const float* ip = input + (size_t)(m0 + mm) * 64 + i0 + ib;
    const float* lp = logj + (size_t)(m0 + mm) * 64 + i0 + ib;
    float4 v0 = *(const float4*)ip, v1 = *(const float4*)(ip + 4);
    float4 g0 = *(const float4*)lp, g1 = *(const float4*)(lp + 4);
    float vi[8] = {v0.x, v0.y, v0.z, v0.w, v1.x, v1.y, v1.z, v1.w};
    float gj[8] = {g0.x, g0.y, g0.z, g0.w, g1.x, g1.y, g1.z, g1.w};
    #pragma unroll
    for (int j = 0; j < 8; ++j) {
      xin_l[(ib + j) * 64 + mm] = vi[j];
      elj_l[(ib + j) * 64 + mm] = f2bf(__expf(gj[j]));
    }
    int il = t >> 3, ob = (t & 7) * 8;
    const float* wp = w_b2 + (size_t)(i0 + il) * 64 + ob;
    float4 e0 = *(const float4*)wp, e1 = *(const float4*)(wp + 4);
    float ev[8] = {e0.x, e0.y, e0.z, e0.w, e1.x, e1.y, e1.z, e1.w};
    #pragma unroll
    for (int j = 0; j < 8; ++j) ewb_l[il * 64 + ob + j] = f2bf(__expf(ev[j]));
  }

  // B-resident: HwT frags (n = m), loop-invariant
  s16x8 bh[4][8];
  #pragma unroll
  for (int nt = 0; nt < 4; ++nt)
    #pragma unroll
    for (int ks = 0; ks < 8; ++ks)
      bh[nt][ks] = *(const s16x8*)(Hw + (size_t)(m0 + nt * 16 + lo) * 256 + ks * 32 + hi * 8);

  __syncthreads();
  asm volatile("s_waitcnt vmcnt(0)" ::: "memory");  // clean vmcnt before counted ring
  __builtin_amdgcn_sched_barrier(0);

  char* Ab = smem + wu * 16384;  // private ring: 16 slots x 1KB
  #pragma unroll
  for (int g = 0; g < 16; ++g)   // prologue: slices i0, i0+1
    stage16(W2F + ((size_t)(i0 + (g >> 3)) * 4 + wu) * 4096 + (size_t)(g & 7) * 512 + (size_t)l * 8,
            Ab + g * 1024);

  f32x4 outa[4] = {{0,0,0,0},{0,0,0,0},{0,0,0,0},{0,0,0,0}};
  f32x4 sea[4] = {{0,0,0,0},{0,0,0,0},{0,0,0,0},{0,0,0,0}};

  for (int il = 0; il < 32; ++il) {
    float xin[4], el[4], ew[4];
    #pragma unroll
    for (int nt = 0; nt < 4; ++nt) {
      xin[nt] = xin_l[il * 64 + nt * 16 + lo];
      el[nt] = bf2f(elj_l[il * 64 + nt * 16 + lo]);
    }
    {
      ushort4 uv = *(const ushort4*)(ewb_l + il * 64 + wu * 16 + hi * 4);
      ew[0] = bf2f(uv.x); ew[1] = bf2f(uv.y); ew[2] = bf2f(uv.z); ew[3] = bf2f(uv.w);
    }
    f32x4 acc[4] = {{0,0,0,0},{0,0,0,0},{0,0,0,0},{0,0,0,0}};
    char* ab = Ab + (il & 1) * 8192;

    // ---- chunk A (ks 0..3): oldest 4 loads must be home ----
    if (il < 31) { WAITV(12); } else { WAITV(4); }
    __builtin_amdgcn_sched_barrier(0);
    #pragma unroll
    for (int ks = 0; ks < 4; ++ks) {
      s16x8 a = *(const s16x8*)(ab + ks * 1024 + l * 16);
      acc[0] = __builtin_amdgcn_mfma_f32_16x16x32_bf16(a, bh[0][ks], acc[0], 0, 0, 0);
      acc[1] = __builtin_amdgcn_mfma_f32_16x16x32_bf16(a, bh[1][ks], acc[1], 0, 0, 0);
      acc[2] = __builtin_amdgcn_mfma_f32_16x16x32_bf16(a, bh[2][ks], acc[2], 0, 0, 0);
      acc[3] = __builtin_amdgcn_mfma_f32_16x16x32_bf16(a, bh[3][ks], acc[3], 0, 0, 0);
    }
    asm volatile("s_waitcnt lgkmcnt(0)" ::: "memory");  // ds_reads retired before WAR
    __builtin_amdgcn_sched_barrier(0);
    if (il < 30) {
      size_t gsrc = ((size_t)(i0 + il + 2) * 4 + wu) * 4096;
      #pragma unroll
      for (int ks = 0; ks < 4; ++ks)
        stage16(W2F + gsrc + (size_t)ks * 512 + (size_t)l * 8, ab + ks * 1024);
    }
    // ---- chunk B (ks 4..7) ----
    if (il < 30) { WAITV(12); } else if (il == 30) { WAITV(8); } else { WAITV(0); }
    __builtin_amdgcn_sched_barrier(0);
    #pragma unroll
    for (int ks = 4; ks < 8; ++ks) {
      s16x8 a = *(const s16x8*)(ab + ks * 1024 + l * 16);
      acc[0] = __builtin_amdgcn_mfma_f32_16x16x32_bf16(a, bh[0][ks], acc[0], 0, 0, 0);
      acc[1] = __builtin_amdgcn_mfma_f32_16x16x32_bf16(a, bh[1][ks], acc[1], 0, 0, 0);
      acc[2] = __builtin_amdgcn_mfma_f32_16x16x32_bf16(a, bh[2][ks], acc[2], 0, 0, 0);
      acc[3] = __builtin_amdgcn_mfma_f32_16x16x32_bf16(a, bh[3][ks], acc[3], 0, 0, 0);
    }
    asm volatile("s_waitcnt lgkmcnt(0)" ::: "memory");
    __builtin_amdgcn_sched_barrier(0);
    if (il < 30) {
      size_t gsrc = ((size_t)(i0 + il + 2) * 4 + wu) * 4096;
      #pragma unroll
      for (int ks = 4; ks < 8; ++ks)
        stage16(W2F + gsrc + (size_t)ks * 512 + (size_t)l * 8, ab + ks * 1024);
    }
    // ---- epilogue (VALU; overlaps in-flight loads) ----
    #pragma unroll
    for (int nt = 0; nt < 4; ++nt)
      #pragma unroll
      for (int r = 0; r < 4; ++r) {
        float e1 = __expf(acc[nt][r]) * ew[r];
        outa[nt][r] = fmaf(xin[nt], e1, outa[nt][r]);
        sea[nt][r] = fmaf(el[nt], e1, sea[nt][r]);
      }
  }

  const int o0 = wu * 16 + hi * 4;
  #pragma unroll
  for (int nt = 0; nt < 4; ++nt) {
    size_t base = (size_t)(m0 + nt * 16 + lo) * 64 + o0;
    *(f32x4*)(Poa + (size_t)iq * 1048576 + base) = outa[nt];
    *(f32x4*)(Pse + (size_t)iq * 1048576 + base) = sea[nt];
  }
}

// ---------------- K2: combine partials ----------------
__global__ __launch_bounds__(256) void k_final(
    const float* __restrict__ b1, const float* __restrict__ Poa,
    const float* __restrict__ Pse, float* __restrict__ out) {
  int idx = (blockIdx.x * 256 + threadIdx.x) * 4;
  float4 bb = *(const float4*)(b1 + idx);
  float4 a0 = *(const float4*)(Poa + idx);
  float4 a1 = *(const float4*)(Poa + 1048576 + idx);
  float4 s0 = *(const float4*)(Pse + idx);
  float4 s1 = *(const float4*)(Pse + 1048576 + idx);
  float4 o1, o2;
  o1.x = bb.x + a0.x + a1.x; o1.y = bb.y + a0.y + a1.y;
  o1.z = bb.z + a0.z + a1.z; o1.w = bb.w + a0.w + a1.w;
  o2.x = __logf(s0.x + s1.x); o2.y = __logf(s0.y + s1.y);
  o2.z = __logf(s0.z + s1.z); o2.w = __logf(s0.w + s1.w);
  *(float4*)(out + idx) = o1;
  *(float4*)(out + 1048576 + idx) = o2;
}

extern "C" void kernel_launch(void* const* d_in, const int* in_sizes, int n_in,
                              void* d_out, int out_size, void* d_ws, size_t ws_size,
                              hipStream_t stream) {
  const float* input = (const float*)d_in[0];
  const float* w_emb = (const float*)d_in[1];
  const float* logj  = (const float*)d_in[2];
  const float* w_w1  = (const float*)d_in[3];
  const float* w_b1  = (const float*)d_in[4];
  const float* w_w2  = (const float*)d_in[5];
  const float* w_b2  = (const float*)d_in[6];
  const float* b_w1  = (const float*)d_in[7];
  const float* b_b1  = (const float*)d_in[8];
  const float* b_w2  = (const float*)d_in[9];
  const float* b_b2  = (const float*)d_in[10];
  float* out = (float*)d_out;

  char* wsb = (char*)d_ws;
  unsigned short* W2F = (unsigned short*)(wsb);
  unsigned short* Hw  = (unsigned short*)(wsb + 2097152);
  float*          b1  = (float*)(wsb + 10485760);
  float*          Poa = (float*)(wsb + 14680064);
  float*          Pse = (float*)(wsb + 23068672);

  hipLaunchKernelGGL(k_pre, dim3(576), dim3(256), 0, stream,
                     w_w2, w_emb, w_w1, w_b1, b_w1, b_b1, b_w2, b_b2, W2F, Hw, b1);
  hipLaunchKernelGGL(k_fused, dim3(512), dim3(256), 0, stream,
                     input, logj, w_b2, W2F, Hw, Poa, Pse);
  hipLaunchKernelGGL(k_final, dim3(1024), dim3(256), 0, stream, b1, Poa, Pse, out);
}